// Round 1
// baseline (3601.287 us; speedup 1.0000x reference)
//
#include <hip/hip_runtime.h>

// ---------------------------------------------------------------------------
// GCN forward: 4 layers, norm precompute shared across layers.
//   norm:  deg[i] = 1 + sum_{e: row=e}=w[e]; dis = rsqrt(deg); norm_e = dis[row]*w*dis[col]
//   layer: h = act_in(x) @ W ; agg = b + dis^2*h (self loop) + scatter_add(norm_e * h[col] -> row)
//   ReLU is applied on-load inside the NEXT layer's GEMM (agg stores pre-activation).
// ---------------------------------------------------------------------------

#define BT 256  // block size for elementwise/scatter kernels

// ---------------- norm precompute ----------------
__global__ void deg_init_kernel(float* deg, int n) {
    int i = blockIdx.x * blockDim.x + threadIdx.x;
    if (i < n) deg[i] = 1.0f;  // self-loop weight
}

__global__ void deg_accum_kernel(const int* __restrict__ row, const float* __restrict__ w,
                                 float* deg, int e) {
    int i = blockIdx.x * blockDim.x + threadIdx.x;
    if (i < e) unsafeAtomicAdd(&deg[row[i]], w[i]);
}

__global__ void dis_kernel(float* deg, int n) {
    int i = blockIdx.x * blockDim.x + threadIdx.x;
    if (i < n) {
        float d = deg[i];
        deg[i] = (d > 0.f) ? rsqrtf(fmaxf(d, 1e-12f)) : 0.f;  // in-place deg -> dis
    }
}

__global__ void norm_kernel(const int* __restrict__ row, const int* __restrict__ col,
                            const float* __restrict__ w, const float* __restrict__ dis,
                            float* __restrict__ norm, int e) {
    int i = blockIdx.x * blockDim.x + threadIdx.x;
    if (i < e) norm[i] = dis[row[i]] * w[i] * dis[col[i]];
}

// ---------------- dense GEMM: H[n,F] = actin(X[n,K]) @ W[K,F] ----------------
// W staged fully in LDS (max 128*100*4 = 51.2 KB). One output column per thread,
// RU rows per iteration staged in LDS, RU register accumulators.
template <int K, int F, int BLK, int RU, bool RELU_IN>
__global__ __launch_bounds__(BLK) void gemm_kernel(const float* __restrict__ X,
                                                   const float* __restrict__ W,
                                                   float* __restrict__ H, int n) {
    __shared__ float Ws[K * F];
    __shared__ float Xs[RU][K];
    const int tid = threadIdx.x;
    for (int i = tid; i < K * F; i += BLK) Ws[i] = W[i];

    const int r_base = blockIdx.x * 128;  // rows per block
    const int r_end = (r_base + 128 < n) ? (r_base + 128) : n;
    for (int r0 = r_base; r0 < r_end; r0 += RU) {
        __syncthreads();  // also covers initial Ws load / prev iter's Xs reads
        for (int i = tid; i < RU * K; i += BLK) {
            int rr = i / K, kk = i - rr * K;
            int r = r0 + rr;
            float v = (r < n) ? X[(long long)r * K + kk] : 0.f;
            if (RELU_IN) v = fmaxf(v, 0.f);
            Xs[rr][kk] = v;
        }
        __syncthreads();
        if (tid < F) {
            float acc[RU];
#pragma unroll
            for (int u = 0; u < RU; ++u) acc[u] = 0.f;
#pragma unroll 4
            for (int k = 0; k < K; ++k) {
                float wv = Ws[k * F + tid];
#pragma unroll
                for (int u = 0; u < RU; ++u) acc[u] += Xs[u][k] * wv;
            }
#pragma unroll
            for (int u = 0; u < RU; ++u) {
                int r = r0 + u;
                if (r < n) H[(long long)r * F + tid] = acc[u];
            }
        }
    }
}

// ---------------- aggregation ----------------
// init: A[i][f] = b[f] + dis[i]^2 * H[i][f]   (self-loop term, atomic-free, full overwrite)
template <int F>
__global__ void agg_init_kernel(const float* __restrict__ H, const float* __restrict__ dis,
                                const float* __restrict__ bias, float* __restrict__ A, int n) {
    int idx = blockIdx.x * blockDim.x + threadIdx.x;
    if (idx >= n * F) return;
    int i = idx / F;
    int f = idx - i * F;
    float d = dis[i];
    A[idx] = bias[f] + d * d * H[idx];
}

// edges: A[row[e]][:] += norm[e] * H[col[e]][:], one thread per (edge, VEC-chunk)
template <int F, int VEC>
__global__ void agg_edges_kernel(const int* __restrict__ row, const int* __restrict__ col,
                                 const float* __restrict__ norm, const float* __restrict__ H,
                                 float* __restrict__ A, int e) {
    constexpr int CPE = F / VEC;  // chunks per edge
    int idx = blockIdx.x * blockDim.x + threadIdx.x;
    if (idx >= e * CPE) return;
    int ed = idx / CPE;
    int c = idx - ed * CPE;
    float nv = norm[ed];
    int src = col[ed], dst = row[ed];
    const float* hp = H + (long long)src * F + c * VEC;
    float* ap = A + (long long)dst * F + c * VEC;
    if constexpr (VEC == 4) {
        float4 h4 = *reinterpret_cast<const float4*>(hp);
        unsafeAtomicAdd(&ap[0], nv * h4.x);
        unsafeAtomicAdd(&ap[1], nv * h4.y);
        unsafeAtomicAdd(&ap[2], nv * h4.z);
        unsafeAtomicAdd(&ap[3], nv * h4.w);
    } else {
        float2 h2 = *reinterpret_cast<const float2*>(hp);
        unsafeAtomicAdd(&ap[0], nv * h2.x);
        unsafeAtomicAdd(&ap[1], nv * h2.y);
    }
}

// ---------------------------------------------------------------------------
extern "C" void kernel_launch(void* const* d_in, const int* in_sizes, int n_in,
                              void* d_out, int out_size, void* d_ws, size_t ws_size,
                              hipStream_t stream) {
    const float* x  = (const float*)d_in[0];
    const int*   ei = (const int*)d_in[1];
    const float* ew = (const float*)d_in[2];
    const float* W0 = (const float*)d_in[3];
    const float* b0 = (const float*)d_in[4];
    const float* W1 = (const float*)d_in[5];
    const float* b1 = (const float*)d_in[6];
    const float* W2 = (const float*)d_in[7];
    const float* b2 = (const float*)d_in[8];
    const float* W3 = (const float*)d_in[9];
    const float* b3 = (const float*)d_in[10];
    float* out = (float*)d_out;

    const int N = in_sizes[0] / 128;  // 50000
    const int E = in_sizes[1] / 2;    // 800000
    const int* row = ei;        // edge_index[0]
    const int* col = ei + E;    // edge_index[1]

    // workspace layout (floats): dis[N] | norm[E] | bufA[N*100] | bufB[N*100]
    float* ws = (float*)d_ws;
    float* dis  = ws;
    float* norm = dis + N;
    float* bufA = norm + E;
    float* bufB = bufA + (size_t)N * 100;

    // ---- norm precompute (shared across layers) ----
    deg_init_kernel<<<(N + BT - 1) / BT, BT, 0, stream>>>(dis, N);
    deg_accum_kernel<<<(E + BT - 1) / BT, BT, 0, stream>>>(row, ew, dis, E);
    dis_kernel<<<(N + BT - 1) / BT, BT, 0, stream>>>(dis, N);
    norm_kernel<<<(E + BT - 1) / BT, BT, 0, stream>>>(row, col, ew, dis, norm, E);

    const int gemm_blocks = (N + 127) / 128;

    // ---- layer 0: x(128) -> 100, relu folded into next GEMM ----
    gemm_kernel<128, 100, 128, 4, false><<<gemm_blocks, 128, 0, stream>>>(x, W0, bufA, N);
    agg_init_kernel<100><<<(N * 100 + BT - 1) / BT, BT, 0, stream>>>(bufA, dis, b0, bufB, N);
    agg_edges_kernel<100, 4><<<(E * 25 + BT - 1) / BT, BT, 0, stream>>>(row, col, norm, bufA, bufB, E);

    // ---- layer 1: 100 -> 100 ----
    gemm_kernel<100, 100, 128, 4, true><<<gemm_blocks, 128, 0, stream>>>(bufB, W1, bufA, N);
    agg_init_kernel<100><<<(N * 100 + BT - 1) / BT, BT, 0, stream>>>(bufA, dis, b1, bufB, N);
    agg_edges_kernel<100, 4><<<(E * 25 + BT - 1) / BT, BT, 0, stream>>>(row, col, norm, bufA, bufB, E);

    // ---- layer 2: 100 -> 50 ----
    gemm_kernel<100, 50, 64, 4, true><<<gemm_blocks, 64, 0, stream>>>(bufB, W2, bufA, N);
    agg_init_kernel<50><<<(N * 50 + BT - 1) / BT, BT, 0, stream>>>(bufA, dis, b2, bufB, N);
    agg_edges_kernel<50, 2><<<(E * 25 + BT - 1) / BT, BT, 0, stream>>>(row, col, norm, bufA, bufB, E);

    // ---- layer 3: 50 -> 6 (no activation on output) ----
    gemm_kernel<50, 6, 64, 4, true><<<gemm_blocks, 64, 0, stream>>>(bufB, W3, bufA, N);
    agg_init_kernel<6><<<(N * 6 + BT - 1) / BT, BT, 0, stream>>>(bufA, dis, b3, out, N);
    agg_edges_kernel<6, 2><<<(E * 3 + BT - 1) / BT, BT, 0, stream>>>(row, col, norm, bufA, out, E);
}

// Round 2
// 1064.797 us; speedup vs baseline: 3.3821x; 3.3821x over previous
//
#include <hip/hip_runtime.h>

// ---------------------------------------------------------------------------
// GCN forward, CSR-based (atomic-free aggregation).
// Per launch: histogram (count + weight-sum per row) -> dis -> prefix scan ->
// CSR fill (col_s/norm_s grouped by destination row) -> per layer:
//   GEMM (W in LDS, ReLU-on-load) then segmented reduce:
//   A[i] = b + dis[i]^2 * H[i] + sum_{e in row i} norm_e * H[col_e]
// One wave (or sub-wave segment) per node, lanes span features, no atomics.
// ---------------------------------------------------------------------------

#define BT 256
#define SCAN_B 256

// ---------------- precompute ----------------
__global__ void init_kernel(int* counts, float* wsum, int n) {
    int i = blockIdx.x * blockDim.x + threadIdx.x;
    if (i < n) { counts[i] = 0; wsum[i] = 1.0f; }  // self-loop weight = 1
}

__global__ void hist_kernel(const int* __restrict__ row, const float* __restrict__ w,
                            int* counts, float* wsum, int e) {
    int i = blockIdx.x * blockDim.x + threadIdx.x;
    if (i < e) {
        int r = row[i];
        atomicAdd(&counts[r], 1);
        unsafeAtomicAdd(&wsum[r], w[i]);
    }
}

__global__ void dis_kernel(float* deg, int n) {  // in-place wsum -> dis
    int i = blockIdx.x * blockDim.x + threadIdx.x;
    if (i < n) {
        float d = deg[i];
        deg[i] = (d > 0.f) ? rsqrtf(fmaxf(d, 1e-12f)) : 0.f;
    }
}

// counts (in rowptr[0..n-1]) -> exclusive scan; bsums[b] = block total
__global__ void scan1_kernel(int* counts, int* bsums, int n) {
    __shared__ int s[SCAN_B];
    int t = threadIdx.x;
    int i = blockIdx.x * SCAN_B + t;
    int v = (i < n) ? counts[i] : 0;
    s[t] = v;
    __syncthreads();
    for (int off = 1; off < SCAN_B; off <<= 1) {
        int x = (t >= off) ? s[t - off] : 0;
        __syncthreads();
        s[t] += x;
        __syncthreads();
    }
    if (i < n) counts[i] = s[t] - v;  // exclusive
    if (t == SCAN_B - 1) bsums[blockIdx.x] = s[t];
}

__global__ void scan2_kernel(int* bsums, int nb) {  // single block, nb <= SCAN_B
    __shared__ int s[SCAN_B];
    int t = threadIdx.x;
    int v = (t < nb) ? bsums[t] : 0;
    s[t] = v;
    __syncthreads();
    for (int off = 1; off < SCAN_B; off <<= 1) {
        int x = (t >= off) ? s[t - off] : 0;
        __syncthreads();
        s[t] += x;
        __syncthreads();
    }
    if (t < nb) bsums[t] = s[t] - v;  // exclusive block offsets
}

__global__ void scan3_kernel(int* rowptr, const int* __restrict__ bsums, int* cursor,
                             int n, int e) {
    int i = blockIdx.x * blockDim.x + threadIdx.x;
    if (i < n) {
        int rp = rowptr[i] + bsums[i / SCAN_B];
        rowptr[i] = rp;
        cursor[i] = rp;  // fill cursor starts at row base
    }
    if (i == 0) rowptr[n] = e;
}

__global__ void fill_kernel(const int* __restrict__ row, const int* __restrict__ col,
                            const float* __restrict__ w, const float* __restrict__ dis,
                            int* cursor, int* __restrict__ col_s, float* __restrict__ norm_s,
                            int e) {
    int i = blockIdx.x * blockDim.x + threadIdx.x;
    if (i >= e) return;
    int r = row[i], c = col[i];
    int dst = atomicAdd(&cursor[r], 1);
    col_s[dst] = c;
    norm_s[dst] = dis[r] * w[i] * dis[c];
}

// ---------------- dense GEMM: H[n,F] = actin(X[n,K]) @ W[K,F] ----------------
template <int K, int F, int BLK, int RU, bool RELU_IN>
__global__ __launch_bounds__(BLK) void gemm_kernel(const float* __restrict__ X,
                                                   const float* __restrict__ W,
                                                   float* __restrict__ H, int n) {
    __shared__ float Ws[K * F];
    __shared__ float Xs[RU][K];
    const int tid = threadIdx.x;
    for (int i = tid; i < K * F; i += BLK) Ws[i] = W[i];

    const int r_base = blockIdx.x * 128;
    const int r_end = (r_base + 128 < n) ? (r_base + 128) : n;
    for (int r0 = r_base; r0 < r_end; r0 += RU) {
        __syncthreads();
        for (int i = tid; i < RU * K; i += BLK) {
            int rr = i / K, kk = i - rr * K;
            int r = r0 + rr;
            float v = (r < n) ? X[(long long)r * K + kk] : 0.f;
            if (RELU_IN) v = fmaxf(v, 0.f);
            Xs[rr][kk] = v;
        }
        __syncthreads();
        if (tid < F) {
            float acc[RU];
#pragma unroll
            for (int u = 0; u < RU; ++u) acc[u] = 0.f;
#pragma unroll 4
            for (int k = 0; k < K; ++k) {
                float wv = Ws[k * F + tid];
#pragma unroll
                for (int u = 0; u < RU; ++u) acc[u] += Xs[u][k] * wv;
            }
#pragma unroll
            for (int u = 0; u < RU; ++u) {
                int r = r0 + u;
                if (r < n) H[(long long)r * F + tid] = acc[u];
            }
        }
    }
}

// ---------------- CSR segmented aggregation (no atomics) ----------------
// TPN threads per node (segment), lane f covers features [VEC*lane, VEC*lane+VEC).
// A[i][:] = bias + dis[i]^2 * H[i][:] + sum_{e in [rowptr[i],rowptr[i+1])} norm_s[e]*H[col_s[e]][:]
template <int F, int TPN, int VEC>
__global__ __launch_bounds__(BT) void agg_csr_kernel(const int* __restrict__ rowptr,
                                                     const int* __restrict__ col_s,
                                                     const float* __restrict__ norm_s,
                                                     const float* __restrict__ H,
                                                     const float* __restrict__ dis,
                                                     const float* __restrict__ bias,
                                                     float* __restrict__ A, int n) {
    int gid = blockIdx.x * blockDim.x + threadIdx.x;
    int node = gid / TPN;
    int lane = threadIdx.x & (TPN - 1);
    if (node >= n) return;
    int f = lane * VEC;
    bool active = (f < F);

    float acc[VEC];
#pragma unroll
    for (int v = 0; v < VEC; ++v) acc[v] = 0.f;

    int beg = rowptr[node], end = rowptr[node + 1];
    for (int e = beg; e < end; ++e) {
        int c = col_s[e];
        float nv = norm_s[e];
        if (active) {
            const float* hp = H + (long long)c * F + f;
#pragma unroll
            for (int v = 0; v < VEC; ++v) acc[v] += nv * hp[v];
        }
    }
    if (active) {
        float d = dis[node];
        float d2 = d * d;
        const float* hself = H + (long long)node * F + f;
        float* ap = A + (long long)node * F + f;
#pragma unroll
        for (int v = 0; v < VEC; ++v) ap[v] = bias[f + v] + d2 * hself[v] + acc[v];
    }
}

// ---------------------------------------------------------------------------
extern "C" void kernel_launch(void* const* d_in, const int* in_sizes, int n_in,
                              void* d_out, int out_size, void* d_ws, size_t ws_size,
                              hipStream_t stream) {
    const float* x  = (const float*)d_in[0];
    const int*   ei = (const int*)d_in[1];
    const float* ew = (const float*)d_in[2];
    const float* W0 = (const float*)d_in[3];
    const float* b0 = (const float*)d_in[4];
    const float* W1 = (const float*)d_in[5];
    const float* b1 = (const float*)d_in[6];
    const float* W2 = (const float*)d_in[7];
    const float* b2 = (const float*)d_in[8];
    const float* W3 = (const float*)d_in[9];
    const float* b3 = (const float*)d_in[10];
    float* out = (float*)d_out;

    const int N = in_sizes[0] / 128;  // 50000
    const int E = in_sizes[1] / 2;    // 800000
    const int* row = ei;
    const int* col = ei + E;

    const int NB = (N + SCAN_B - 1) / SCAN_B;  // 196 <= 256

    // workspace layout:
    // dis[N] f | rowptr[N+1] i | cursor[N] i | bsums[SCAN_B] i |
    // col_s[E] i | norm_s[E] f | bufA[N*100] f | bufB[N*100] f
    float* ws = (float*)d_ws;
    float* dis    = ws;
    int*   rowptr = (int*)(dis + N);
    int*   cursor = rowptr + (N + 1);
    int*   bsums  = cursor + N;
    int*   col_s  = bsums + SCAN_B;
    float* norm_s = (float*)(col_s + E);
    float* bufA   = norm_s + E;
    float* bufB   = bufA + (size_t)N * 100;

    // ---- CSR + norm precompute ----
    init_kernel<<<(N + BT - 1) / BT, BT, 0, stream>>>(rowptr, dis, N);
    hist_kernel<<<(E + BT - 1) / BT, BT, 0, stream>>>(row, ew, rowptr, dis, E);
    dis_kernel<<<(N + BT - 1) / BT, BT, 0, stream>>>(dis, N);
    scan1_kernel<<<NB, SCAN_B, 0, stream>>>(rowptr, bsums, N);
    scan2_kernel<<<1, SCAN_B, 0, stream>>>(bsums, NB);
    scan3_kernel<<<(N + BT - 1) / BT, BT, 0, stream>>>(rowptr, bsums, cursor, N, E);
    fill_kernel<<<(E + BT - 1) / BT, BT, 0, stream>>>(row, col, ew, dis, cursor, col_s, norm_s, E);

    const int gemm_blocks = (N + 127) / 128;
    const int agg64_blocks = (N * 64 + BT - 1) / BT;   // one wave per node
    const int agg8_blocks  = (N * 8 + BT - 1) / BT;    // 8 threads per node

    // ---- layer 0: x(128) -> 100 ----
    gemm_kernel<128, 100, 128, 4, false><<<gemm_blocks, 128, 0, stream>>>(x, W0, bufA, N);
    agg_csr_kernel<100, 64, 2><<<agg64_blocks, BT, 0, stream>>>(rowptr, col_s, norm_s, bufA, dis, b0, bufB, N);

    // ---- layer 1: 100 -> 100 ----
    gemm_kernel<100, 100, 128, 4, true><<<gemm_blocks, 128, 0, stream>>>(bufB, W1, bufA, N);
    agg_csr_kernel<100, 64, 2><<<agg64_blocks, BT, 0, stream>>>(rowptr, col_s, norm_s, bufA, dis, b1, bufB, N);

    // ---- layer 2: 100 -> 50 ----
    gemm_kernel<100, 50, 64, 4, true><<<gemm_blocks, 64, 0, stream>>>(bufB, W2, bufA, N);
    agg_csr_kernel<50, 64, 1><<<agg64_blocks, BT, 0, stream>>>(rowptr, col_s, norm_s, bufA, dis, b2, bufB, N);

    // ---- layer 3: 50 -> 6 ----
    gemm_kernel<50, 6, 64, 4, true><<<gemm_blocks, 64, 0, stream>>>(bufB, W3, bufA, N);
    agg_csr_kernel<6, 8, 1><<<agg8_blocks, BT, 0, stream>>>(rowptr, col_s, norm_s, bufA, dis, b3, out, N);
}

// Round 3
// 605.577 us; speedup vs baseline: 5.9469x; 1.7583x over previous
//
#include <hip/hip_runtime.h>

// ---------------------------------------------------------------------------
// GCN forward, CSR aggregation + register-tiled fp32 GEMM.
//   GEMM: 256 thr/block, each thread 4 rows x 4 cols, k unrolled by 4.
//         W staged in LDS (zero-padded to 4-col groups); X read direct from
//         global (block's 40-row slice is L1-resident, reused by 25 col-groups).
//   agg:  A[i] = b + dis[i]^2*H[i] + sum_{e in row i} norm_e * H[col_e]  (CSR, no atomics)
//   ReLU folded into next layer's GEMM load.
// ---------------------------------------------------------------------------

#define BT 256
#define SCAN_B 256

// ---------------- precompute ----------------
__global__ void init_kernel(int* counts, float* wsum, int n) {
    int i = blockIdx.x * blockDim.x + threadIdx.x;
    if (i < n) { counts[i] = 0; wsum[i] = 1.0f; }  // self-loop weight = 1
}

__global__ void hist_kernel(const int* __restrict__ row, const float* __restrict__ w,
                            int* counts, float* wsum, int e) {
    int i = blockIdx.x * blockDim.x + threadIdx.x;
    if (i < e) {
        int r = row[i];
        atomicAdd(&counts[r], 1);
        unsafeAtomicAdd(&wsum[r], w[i]);
    }
}

__global__ void dis_kernel(float* deg, int n) {  // in-place wsum -> dis
    int i = blockIdx.x * blockDim.x + threadIdx.x;
    if (i < n) {
        float d = deg[i];
        deg[i] = (d > 0.f) ? rsqrtf(fmaxf(d, 1e-12f)) : 0.f;
    }
}

__global__ void scan1_kernel(int* counts, int* bsums, int n) {
    __shared__ int s[SCAN_B];
    int t = threadIdx.x;
    int i = blockIdx.x * SCAN_B + t;
    int v = (i < n) ? counts[i] : 0;
    s[t] = v;
    __syncthreads();
    for (int off = 1; off < SCAN_B; off <<= 1) {
        int x = (t >= off) ? s[t - off] : 0;
        __syncthreads();
        s[t] += x;
        __syncthreads();
    }
    if (i < n) counts[i] = s[t] - v;  // exclusive
    if (t == SCAN_B - 1) bsums[blockIdx.x] = s[t];
}

__global__ void scan2_kernel(int* bsums, int nb) {  // single block, nb <= SCAN_B
    __shared__ int s[SCAN_B];
    int t = threadIdx.x;
    int v = (t < nb) ? bsums[t] : 0;
    s[t] = v;
    __syncthreads();
    for (int off = 1; off < SCAN_B; off <<= 1) {
        int x = (t >= off) ? s[t - off] : 0;
        __syncthreads();
        s[t] += x;
        __syncthreads();
    }
    if (t < nb) bsums[t] = s[t] - v;
}

__global__ void scan3_kernel(int* rowptr, const int* __restrict__ bsums, int* cursor,
                             int n, int e) {
    int i = blockIdx.x * blockDim.x + threadIdx.x;
    if (i < n) {
        int rp = rowptr[i] + bsums[i / SCAN_B];
        rowptr[i] = rp;
        cursor[i] = rp;
    }
    if (i == 0) rowptr[n] = e;
}

__global__ void fill_kernel(const int* __restrict__ row, const int* __restrict__ col,
                            const float* __restrict__ w, const float* __restrict__ dis,
                            int* cursor, int* __restrict__ col_s, float* __restrict__ norm_s,
                            int e) {
    int i = blockIdx.x * blockDim.x + threadIdx.x;
    if (i >= e) return;
    int r = row[i], c = col[i];
    int dst = atomicAdd(&cursor[r], 1);
    col_s[dst] = c;
    norm_s[dst] = dis[r] * w[i] * dis[c];
}

// ---------------- register-tiled GEMM: H[n,F] = actin(X[n,K]) @ W[K,F] --------
// Requires K % 4 == 0 and X rows 16B-aligned (K % 4 == 0 guarantees it).
template <int K, int F, bool RELU_IN>
__global__ __launch_bounds__(256) void gemm_tile_kernel(const float* __restrict__ X,
                                                        const float* __restrict__ W,
                                                        float* __restrict__ H, int n) {
    static_assert(K % 4 == 0, "K must be multiple of 4");
    constexpr int NCG = (F + 3) / 4;   // col groups of 4
    constexpr int FP = NCG * 4;        // padded col count (LDS stride)
    constexpr int RG = 256 / NCG;      // row groups per block
    constexpr int ROWS = RG * 4;       // rows per block

    __shared__ float Ws[K * FP];
    const int tid = threadIdx.x;
    for (int i = tid; i < K * FP; i += 256) {
        int k = i / FP, c = i - k * FP;
        Ws[i] = (c < F) ? W[k * F + c] : 0.f;  // zero-pad cols F..FP
    }
    __syncthreads();

    const int txc = tid % NCG;   // col group
    const int tyr = tid / NCG;   // row group
    if (tyr >= RG) return;       // (after the only __syncthreads)

    const int r0 = blockIdx.x * ROWS + tyr * 4;
    bool rv[4];
    const float* xrow[4];
#pragma unroll
    for (int i = 0; i < 4; ++i) {
        int r = r0 + i;
        rv[i] = (r < n);
        xrow[i] = X + (long long)(rv[i] ? r : 0) * K;
    }

    float acc[4][4] = {};
    const float* wbase = &Ws[txc * 4];
    for (int k = 0; k < K; k += 4) {
        float4 w0 = *reinterpret_cast<const float4*>(wbase + (k + 0) * FP);
        float4 w1 = *reinterpret_cast<const float4*>(wbase + (k + 1) * FP);
        float4 w2 = *reinterpret_cast<const float4*>(wbase + (k + 2) * FP);
        float4 w3 = *reinterpret_cast<const float4*>(wbase + (k + 3) * FP);
#pragma unroll
        for (int i = 0; i < 4; ++i) {
            float4 x4 = *reinterpret_cast<const float4*>(xrow[i] + k);
            if (RELU_IN) {
                x4.x = fmaxf(x4.x, 0.f); x4.y = fmaxf(x4.y, 0.f);
                x4.z = fmaxf(x4.z, 0.f); x4.w = fmaxf(x4.w, 0.f);
            }
            acc[i][0] += x4.x * w0.x + x4.y * w1.x + x4.z * w2.x + x4.w * w3.x;
            acc[i][1] += x4.x * w0.y + x4.y * w1.y + x4.z * w2.y + x4.w * w3.y;
            acc[i][2] += x4.x * w0.z + x4.y * w1.z + x4.z * w2.z + x4.w * w3.z;
            acc[i][3] += x4.x * w0.w + x4.y * w1.w + x4.z * w2.w + x4.w * w3.w;
        }
    }

#pragma unroll
    for (int i = 0; i < 4; ++i) {
        if (!rv[i]) continue;
        long long base = (long long)(r0 + i) * F + txc * 4;
#pragma unroll
        for (int j = 0; j < 4; ++j)
            if (txc * 4 + j < F) H[base + j] = acc[i][j];
    }
}

// thread-per-row GEMV for tiny F (layer 3: K=50, F=6). K must be even.
template <int K, int F, bool RELU_IN>
__global__ __launch_bounds__(256) void gemv_rows_kernel(const float* __restrict__ X,
                                                        const float* __restrict__ W,
                                                        float* __restrict__ H, int n) {
    static_assert(K % 2 == 0, "K must be even");
    __shared__ float Ws[K * F];
    const int tid = threadIdx.x;
    for (int i = tid; i < K * F; i += 256) Ws[i] = W[i];
    __syncthreads();
    int r = blockIdx.x * 256 + tid;
    if (r >= n) return;
    float acc[F] = {};
    const float* xp = X + (long long)r * K;
    for (int k = 0; k < K; k += 2) {
        float2 x2 = *reinterpret_cast<const float2*>(xp + k);
        if (RELU_IN) { x2.x = fmaxf(x2.x, 0.f); x2.y = fmaxf(x2.y, 0.f); }
#pragma unroll
        for (int j = 0; j < F; ++j)
            acc[j] += x2.x * Ws[k * F + j] + x2.y * Ws[(k + 1) * F + j];
    }
    long long base = (long long)r * F;
#pragma unroll
    for (int j = 0; j < F; ++j) H[base + j] = acc[j];
}

// ---------------- CSR segmented aggregation (no atomics) ----------------
template <int F, int TPN, int VEC>
__global__ __launch_bounds__(BT) void agg_csr_kernel(const int* __restrict__ rowptr,
                                                     const int* __restrict__ col_s,
                                                     const float* __restrict__ norm_s,
                                                     const float* __restrict__ H,
                                                     const float* __restrict__ dis,
                                                     const float* __restrict__ bias,
                                                     float* __restrict__ A, int n) {
    int gid = blockIdx.x * blockDim.x + threadIdx.x;
    int node = gid / TPN;
    int lane = threadIdx.x & (TPN - 1);
    if (node >= n) return;
    int f = lane * VEC;
    bool active = (f < F);

    float acc[VEC];
#pragma unroll
    for (int v = 0; v < VEC; ++v) acc[v] = 0.f;

    int beg = rowptr[node], end = rowptr[node + 1];
    for (int e = beg; e < end; ++e) {
        int c = col_s[e];
        float nv = norm_s[e];
        if (active) {
            const float* hp = H + (long long)c * F + f;
#pragma unroll
            for (int v = 0; v < VEC; ++v) acc[v] += nv * hp[v];
        }
    }
    if (active) {
        float d = dis[node];
        float d2 = d * d;
        const float* hself = H + (long long)node * F + f;
        float* ap = A + (long long)node * F + f;
#pragma unroll
        for (int v = 0; v < VEC; ++v) ap[v] = bias[f + v] + d2 * hself[v] + acc[v];
    }
}

// ---------------------------------------------------------------------------
extern "C" void kernel_launch(void* const* d_in, const int* in_sizes, int n_in,
                              void* d_out, int out_size, void* d_ws, size_t ws_size,
                              hipStream_t stream) {
    const float* x  = (const float*)d_in[0];
    const int*   ei = (const int*)d_in[1];
    const float* ew = (const float*)d_in[2];
    const float* W0 = (const float*)d_in[3];
    const float* b0 = (const float*)d_in[4];
    const float* W1 = (const float*)d_in[5];
    const float* b1 = (const float*)d_in[6];
    const float* W2 = (const float*)d_in[7];
    const float* b2 = (const float*)d_in[8];
    const float* W3 = (const float*)d_in[9];
    const float* b3 = (const float*)d_in[10];
    float* out = (float*)d_out;

    const int N = in_sizes[0] / 128;  // 50000
    const int E = in_sizes[1] / 2;    // 800000
    const int* row = ei;
    const int* col = ei + E;

    const int NB = (N + SCAN_B - 1) / SCAN_B;

    // workspace: dis[N] f | rowptr[N+1] i | cursor[N] i | bsums[SCAN_B] i |
    //            col_s[E] i | norm_s[E] f | bufA[N*100] f | bufB[N*100] f
    float* ws = (float*)d_ws;
    float* dis    = ws;
    int*   rowptr = (int*)(dis + N);
    int*   cursor = rowptr + (N + 1);
    int*   bsums  = cursor + N;
    int*   col_s  = bsums + SCAN_B;
    float* norm_s = (float*)(col_s + E);
    float* bufA   = norm_s + E;
    float* bufB   = bufA + (size_t)N * 100;

    // ---- CSR + norm precompute ----
    init_kernel<<<(N + BT - 1) / BT, BT, 0, stream>>>(rowptr, dis, N);
    hist_kernel<<<(E + BT - 1) / BT, BT, 0, stream>>>(row, ew, rowptr, dis, E);
    dis_kernel<<<(N + BT - 1) / BT, BT, 0, stream>>>(dis, N);
    scan1_kernel<<<NB, SCAN_B, 0, stream>>>(rowptr, bsums, N);
    scan2_kernel<<<1, SCAN_B, 0, stream>>>(bsums, NB);
    scan3_kernel<<<(N + BT - 1) / BT, BT, 0, stream>>>(rowptr, bsums, cursor, N, E);
    fill_kernel<<<(E + BT - 1) / BT, BT, 0, stream>>>(row, col, ew, dis, cursor, col_s, norm_s, E);

    const int agg64_blocks = (N * 64 + BT - 1) / BT;
    const int agg8_blocks  = (N * 8 + BT - 1) / BT;

    // rows/block: F=100 -> NCG=25, RG=10, ROWS=40; F=50 -> NCG=13, RG=19, ROWS=76
    const int g100_blocks = (N + 39) / 40;   // 1250
    const int g50_blocks  = (N + 75) / 76;   // 658

    // ---- layer 0: x(128) -> 100 ----
    gemm_tile_kernel<128, 100, false><<<g100_blocks, 256, 0, stream>>>(x, W0, bufA, N);
    agg_csr_kernel<100, 64, 2><<<agg64_blocks, BT, 0, stream>>>(rowptr, col_s, norm_s, bufA, dis, b0, bufB, N);

    // ---- layer 1: 100 -> 100 ----
    gemm_tile_kernel<100, 100, true><<<g100_blocks, 256, 0, stream>>>(bufB, W1, bufA, N);
    agg_csr_kernel<100, 64, 2><<<agg64_blocks, BT, 0, stream>>>(rowptr, col_s, norm_s, bufA, dis, b1, bufB, N);

    // ---- layer 2: 100 -> 50 ----
    gemm_tile_kernel<100, 50, true><<<g50_blocks, 256, 0, stream>>>(bufB, W2, bufA, N);
    agg_csr_kernel<50, 64, 1><<<agg64_blocks, BT, 0, stream>>>(rowptr, col_s, norm_s, bufA, dis, b2, bufB, N);

    // ---- layer 3: 50 -> 6 ----
    gemv_rows_kernel<50, 6, true><<<(N + 255) / 256, 256, 0, stream>>>(bufB, W3, bufA, N);
    agg_csr_kernel<6, 8, 1><<<agg8_blocks, BT, 0, stream>>>(rowptr, col_s, norm_s, bufA, dis, b3, out, N);
}

// Round 4
// 535.187 us; speedup vs baseline: 6.7290x; 1.1315x over previous
//
#include <hip/hip_runtime.h>

// ---------------------------------------------------------------------------
// GCN forward: CSR aggregation with L2-resident feature-chunk blocking.
//   H stored chunked: Hc[pass][N][CH] (F=100: 5x20 -> 4.0MB/slice = 1 XCD L2;
//   F=50: 2x25). agg pass p gathers only slice p -> L2 hits instead of L3/HBM.
//   Edge (col,norm) packed int2; sub-wave shfl-broadcast + 4x unrolled gathers.
//   GEMM: register-tiled 4x4/thread, W in LDS, writes chunked layout, ReLU
//   folded into next layer's load. No atomics in any hot path.
// ---------------------------------------------------------------------------

#define BT 256
#define SCAN_B 256

// ---------------- precompute ----------------
__global__ void init_kernel(int* counts, float* wsum, int n) {
    int i = blockIdx.x * blockDim.x + threadIdx.x;
    if (i < n) { counts[i] = 0; wsum[i] = 1.0f; }  // self-loop weight = 1
}

__global__ void hist_kernel(const int* __restrict__ row, const float* __restrict__ w,
                            int* counts, float* wsum, int e) {
    int i = blockIdx.x * blockDim.x + threadIdx.x;
    if (i < e) {
        int r = row[i];
        atomicAdd(&counts[r], 1);
        unsafeAtomicAdd(&wsum[r], w[i]);
    }
}

// exclusive scan of counts (in rowptr[0..n-1]); also wsum -> dis in-place
__global__ void scan1_kernel(int* counts, int* bsums, float* deg, int n) {
    __shared__ int s[SCAN_B];
    int t = threadIdx.x;
    int i = blockIdx.x * SCAN_B + t;
    int v = (i < n) ? counts[i] : 0;
    s[t] = v;
    __syncthreads();
    for (int off = 1; off < SCAN_B; off <<= 1) {
        int x = (t >= off) ? s[t - off] : 0;
        __syncthreads();
        s[t] += x;
        __syncthreads();
    }
    if (i < n) {
        counts[i] = s[t] - v;  // exclusive
        float d = deg[i];
        deg[i] = (d > 0.f) ? rsqrtf(fmaxf(d, 1e-12f)) : 0.f;
    }
    if (t == SCAN_B - 1) bsums[blockIdx.x] = s[t];
}

__global__ void scan2_kernel(int* bsums, int nb) {  // single block, nb <= SCAN_B
    __shared__ int s[SCAN_B];
    int t = threadIdx.x;
    int v = (t < nb) ? bsums[t] : 0;
    s[t] = v;
    __syncthreads();
    for (int off = 1; off < SCAN_B; off <<= 1) {
        int x = (t >= off) ? s[t - off] : 0;
        __syncthreads();
        s[t] += x;
        __syncthreads();
    }
    if (t < nb) bsums[t] = s[t] - v;
}

__global__ void scan3_kernel(int* rowptr, const int* __restrict__ bsums, int* cursor,
                             int n, int e) {
    int i = blockIdx.x * blockDim.x + threadIdx.x;
    if (i < n) {
        int rp = rowptr[i] + bsums[i / SCAN_B];
        rowptr[i] = rp;
        cursor[i] = rp;
    }
    if (i == 0) rowptr[n] = e;
}

__global__ void fill_kernel(const int* __restrict__ row, const int* __restrict__ col,
                            const float* __restrict__ w, const float* __restrict__ dis,
                            int* cursor, int2* __restrict__ epack, int e) {
    int i = blockIdx.x * blockDim.x + threadIdx.x;
    if (i >= e) return;
    int r = row[i], c = col[i];
    float nv = dis[r] * w[i] * dis[c];
    int dst = atomicAdd(&cursor[r], 1);
    epack[dst] = make_int2(c, __float_as_int(nv));  // one 8B scatter
}

// ---------------- register-tiled GEMM: Hc = chunked(actin(X) @ W) ------------
// X row-major [n,K] (K%4==0); output chunked Hc[c/CH][n][CH] (CH divides F or not, per-elem addr).
template <int K, int F, int CH, bool RELU_IN>
__global__ __launch_bounds__(256) void gemm_tile_kernel(const float* __restrict__ X,
                                                        const float* __restrict__ W,
                                                        float* __restrict__ Hc, int n) {
    static_assert(K % 4 == 0, "K must be multiple of 4");
    constexpr int NCG = (F + 3) / 4;
    constexpr int FP = NCG * 4;
    constexpr int RG = 256 / NCG;
    constexpr int ROWS = RG * 4;

    __shared__ float Ws[K * FP];
    const int tid = threadIdx.x;
    for (int i = tid; i < K * FP; i += 256) {
        int k = i / FP, c = i - k * FP;
        Ws[i] = (c < F) ? W[k * F + c] : 0.f;
    }
    __syncthreads();

    const int txc = tid % NCG;
    const int tyr = tid / NCG;
    if (tyr >= RG) return;

    const int r0 = blockIdx.x * ROWS + tyr * 4;
    bool rv[4];
    const float* xrow[4];
#pragma unroll
    for (int i = 0; i < 4; ++i) {
        int r = r0 + i;
        rv[i] = (r < n);
        xrow[i] = X + (long long)(rv[i] ? r : 0) * K;
    }

    float acc[4][4] = {};
    const float* wbase = &Ws[txc * 4];
    for (int k = 0; k < K; k += 4) {
        float4 w0 = *reinterpret_cast<const float4*>(wbase + (k + 0) * FP);
        float4 w1 = *reinterpret_cast<const float4*>(wbase + (k + 1) * FP);
        float4 w2 = *reinterpret_cast<const float4*>(wbase + (k + 2) * FP);
        float4 w3 = *reinterpret_cast<const float4*>(wbase + (k + 3) * FP);
#pragma unroll
        for (int i = 0; i < 4; ++i) {
            float4 x4 = *reinterpret_cast<const float4*>(xrow[i] + k);
            if (RELU_IN) {
                x4.x = fmaxf(x4.x, 0.f); x4.y = fmaxf(x4.y, 0.f);
                x4.z = fmaxf(x4.z, 0.f); x4.w = fmaxf(x4.w, 0.f);
            }
            acc[i][0] += x4.x * w0.x + x4.y * w1.x + x4.z * w2.x + x4.w * w3.x;
            acc[i][1] += x4.x * w0.y + x4.y * w1.y + x4.z * w2.y + x4.w * w3.y;
            acc[i][2] += x4.x * w0.z + x4.y * w1.z + x4.z * w2.z + x4.w * w3.z;
            acc[i][3] += x4.x * w0.w + x4.y * w1.w + x4.z * w2.w + x4.w * w3.w;
        }
    }

#pragma unroll
    for (int i = 0; i < 4; ++i) {
        if (!rv[i]) continue;
        long long r = r0 + i;
#pragma unroll
        for (int j = 0; j < 4; ++j) {
            int c = txc * 4 + j;
            if (c < F)
                Hc[(size_t)(c / CH) * n * CH + r * CH + (c % CH)] = acc[i][j];
        }
    }
}

// thread-per-row GEMV for tiny F (layer 3: K=50, F=6), row-major output.
template <int K, int F, bool RELU_IN>
__global__ __launch_bounds__(256) void gemv_rows_kernel(const float* __restrict__ X,
                                                        const float* __restrict__ W,
                                                        float* __restrict__ H, int n) {
    static_assert(K % 2 == 0, "K must be even");
    __shared__ float Ws[K * F];
    const int tid = threadIdx.x;
    for (int i = tid; i < K * F; i += 256) Ws[i] = W[i];
    __syncthreads();
    int r = blockIdx.x * 256 + tid;
    if (r >= n) return;
    float acc[F] = {};
    const float* xp = X + (long long)r * K;
    for (int k = 0; k < K; k += 2) {
        float2 x2 = *reinterpret_cast<const float2*>(xp + k);
        if (RELU_IN) { x2.x = fmaxf(x2.x, 0.f); x2.y = fmaxf(x2.y, 0.f); }
#pragma unroll
        for (int j = 0; j < F; ++j)
            acc[j] += x2.x * Ws[k * F + j] + x2.y * Ws[(k + 1) * F + j];
    }
    long long base = (long long)r * F;
#pragma unroll
    for (int j = 0; j < F; ++j) H[base + j] = acc[j];
}

// ---------------- chunked CSR aggregation ----------------
// grid = (ceil(n/(BT/TPN)), NPASS); pass p gathers only slice Hc[p] (L2-resident).
// A[i][p*CH+lane] = bias + dis[i]^2*Hc[p][i][lane] + sum_e norm_e*Hc[p][col_e][lane]
template <int F, int CH, int TPN>
__global__ __launch_bounds__(BT) void agg_chunk_kernel(const int* __restrict__ rowptr,
                                                       const int2* __restrict__ epack,
                                                       const float* __restrict__ H,
                                                       const float* __restrict__ dis,
                                                       const float* __restrict__ bias,
                                                       float* __restrict__ A, int n) {
    const int tid = threadIdx.x;
    const int node = blockIdx.x * (BT / TPN) + tid / TPN;
    const int lane = tid & (TPN - 1);
    if (node >= n) return;
    const int pass = blockIdx.y;
    const float* __restrict__ Hc = H + (size_t)pass * n * CH;

    float acc = 0.f;
    const int beg = rowptr[node], end = rowptr[node + 1];
    for (int base = beg; base < end; base += TPN) {
        int m = end - base;
        if (m > TPN) m = TPN;
        int2 ed = (lane < m) ? epack[base + lane] : make_int2(0, 0);
        int myc = ed.x;
        float myn = __int_as_float(ed.y);
        int j = 0;
        for (; j + 4 <= m; j += 4) {
            int c0 = __shfl(myc, j, TPN);     float n0 = __shfl(myn, j, TPN);
            int c1 = __shfl(myc, j + 1, TPN); float n1 = __shfl(myn, j + 1, TPN);
            int c2 = __shfl(myc, j + 2, TPN); float n2 = __shfl(myn, j + 2, TPN);
            int c3 = __shfl(myc, j + 3, TPN); float n3 = __shfl(myn, j + 3, TPN);
            if (lane < CH) {
                float h0 = Hc[(size_t)c0 * CH + lane];
                float h1 = Hc[(size_t)c1 * CH + lane];
                float h2 = Hc[(size_t)c2 * CH + lane];
                float h3 = Hc[(size_t)c3 * CH + lane];
                acc += n0 * h0;
                acc += n1 * h1;
                acc += n2 * h2;
                acc += n3 * h3;
            }
        }
        for (; j < m; ++j) {
            int c = __shfl(myc, j, TPN);
            float nv = __shfl(myn, j, TPN);
            if (lane < CH) acc += nv * Hc[(size_t)c * CH + lane];
        }
    }
    if (lane < CH) {
        int f = pass * CH + lane;
        float d = dis[node];
        A[(size_t)node * F + f] = bias[f] + d * d * Hc[(size_t)node * CH + lane] + acc;
    }
}

// simple per-node agg for tiny F (row-major H), packed edges
template <int F, int TPN>
__global__ __launch_bounds__(BT) void agg_small_kernel(const int* __restrict__ rowptr,
                                                       const int2* __restrict__ epack,
                                                       const float* __restrict__ H,
                                                       const float* __restrict__ dis,
                                                       const float* __restrict__ bias,
                                                       float* __restrict__ A, int n) {
    int gid = blockIdx.x * blockDim.x + threadIdx.x;
    int node = gid / TPN;
    int lane = threadIdx.x & (TPN - 1);
    if (node >= n) return;
    bool active = (lane < F);
    float acc = 0.f;
    int beg = rowptr[node], end = rowptr[node + 1];
    for (int e = beg; e < end; ++e) {
        int2 ed = epack[e];
        if (active) acc += __int_as_float(ed.y) * H[(size_t)ed.x * F + lane];
    }
    if (active) {
        float d = dis[node];
        A[(size_t)node * F + lane] = bias[lane] + d * d * H[(size_t)node * F + lane] + acc;
    }
}

// ---------------------------------------------------------------------------
extern "C" void kernel_launch(void* const* d_in, const int* in_sizes, int n_in,
                              void* d_out, int out_size, void* d_ws, size_t ws_size,
                              hipStream_t stream) {
    const float* x  = (const float*)d_in[0];
    const int*   ei = (const int*)d_in[1];
    const float* ew = (const float*)d_in[2];
    const float* W0 = (const float*)d_in[3];
    const float* b0 = (const float*)d_in[4];
    const float* W1 = (const float*)d_in[5];
    const float* b1 = (const float*)d_in[6];
    const float* W2 = (const float*)d_in[7];
    const float* b2 = (const float*)d_in[8];
    const float* W3 = (const float*)d_in[9];
    const float* b3 = (const float*)d_in[10];
    float* out = (float*)d_out;

    const int N = in_sizes[0] / 128;  // 50000
    const int E = in_sizes[1] / 2;    // 800000
    const int* row = ei;
    const int* col = ei + E;

    const int NB = (N + SCAN_B - 1) / SCAN_B;

    // workspace: dis[N] f | rowptr[N+1] i | cursor[N] i | bsums[SCAN_B] i |
    //            epack[E] int2 | bufA[N*100] f | bufB[N*100] f
    float* ws = (float*)d_ws;
    float* dis    = ws;
    int*   rowptr = (int*)(dis + N);
    int*   cursor = rowptr + (N + 1);
    int*   bsums  = cursor + N;
    int2*  epack  = (int2*)(bsums + SCAN_B);
    float* bufA   = (float*)(epack + E);
    float* bufB   = bufA + (size_t)N * 100;

    // ---- CSR + norm precompute ----
    init_kernel<<<(N + BT - 1) / BT, BT, 0, stream>>>(rowptr, dis, N);
    hist_kernel<<<(E + BT - 1) / BT, BT, 0, stream>>>(row, ew, rowptr, dis, E);
    scan1_kernel<<<NB, SCAN_B, 0, stream>>>(rowptr, bsums, dis, N);
    scan2_kernel<<<1, SCAN_B, 0, stream>>>(bsums, NB);
    scan3_kernel<<<(N + BT - 1) / BT, BT, 0, stream>>>(rowptr, bsums, cursor, N, E);
    fill_kernel<<<(E + BT - 1) / BT, BT, 0, stream>>>(row, col, ew, dis, cursor, epack, E);

    // GEMM rows/block: F=100 -> NCG=25, ROWS=40; F=50 -> NCG=13, ROWS=76
    const int g100_blocks = (N + 39) / 40;
    const int g50_blocks  = (N + 75) / 76;

    // agg grids: TPN=32 -> 8 nodes/block
    const dim3 agg100_grid((N + 7) / 8, 5);  // CH=20, 5 passes (4.0 MB slice)
    const dim3 agg50_grid((N + 7) / 8, 2);   // CH=25, 2 passes (5.0 MB slice)
    const int  agg6_blocks = (N * 8 + BT - 1) / BT;

    // ---- layer 0: x(128) -> 100 ----
    gemm_tile_kernel<128, 100, 20, false><<<g100_blocks, 256, 0, stream>>>(x, W0, bufA, N);
    agg_chunk_kernel<100, 20, 32><<<agg100_grid, BT, 0, stream>>>(rowptr, epack, bufA, dis, b0, bufB, N);

    // ---- layer 1: 100 -> 100 ----
    gemm_tile_kernel<100, 100, 20, true><<<g100_blocks, 256, 0, stream>>>(bufB, W1, bufA, N);
    agg_chunk_kernel<100, 20, 32><<<agg100_grid, BT, 0, stream>>>(rowptr, epack, bufA, dis, b1, bufB, N);

    // ---- layer 2: 100 -> 50 ----
    gemm_tile_kernel<100, 50, 25, true><<<g50_blocks, 256, 0, stream>>>(bufB, W2, bufA, N);
    agg_chunk_kernel<50, 25, 32><<<agg50_grid, BT, 0, stream>>>(rowptr, epack, bufA, dis, b2, bufB, N);

    // ---- layer 3: 50 -> 6 ----
    gemv_rows_kernel<50, 6, true><<<(N + 255) / 256, 256, 0, stream>>>(bufB, W3, bufA, N);
    agg_small_kernel<6, 8><<<agg6_blocks, BT, 0, stream>>>(rowptr, epack, bufA, dis, b3, out, N);
}